// Round 2
// baseline (390.810 us; speedup 1.0000x reference)
//
#include <hip/hip_runtime.h>
#include <math.h>

// FourierFeatureMLP fused kernel for MI355X (gfx950). Round 2.
//
// Dtype resolution: inputs/outputs are FP32 (reference dtype; round-1 NaN
// proved bf16 misread — fp32 mantissa halves decode as Inf/NaN bf16).
// Comparison is done in bf16 (2% threshold), so fp16 MFMA internally is
// plenty of precision (11-bit mantissa, all values bounded |x| <= ~100).
//
// Structure: pre-pass converts W_in + W_h (8 x 256 x 256 fp32) to fp16 in
// d_ws. Main kernel: each block owns TILE_N=128 points; activation h
// [128 x 256] lives in LDS as fp16 across all 8 dense layers; fp16 weights
// are read from d_ws (L2-resident, ~1 MB) as MFMA B-fragments. Only tx
// (1 MB), out (512 KB) and the weight conversion touch HBM.
//
// MFMA 16x16x32 layouts (learn_hip-verified, dtype-independent):
//   A:   lane holds A[m = lane&15][k = (lane>>4)*8 + j], j=0..7
//   B:   lane holds B[k = (lane>>4)*8 + j][n = lane&15]  (= row n of W[o][k])
//   C/D: col = lane&15, row = (lane>>4)*4 + reg
//
// LDS h uses a 16B-chunk XOR swizzle to break the 512 B row-stride bank
// pattern for A-fragment ds_read_b128 (16-way conflict otherwise).

#define HDIM   256
#define NFREQ  128
#define NLAYER 8           // W_in layer + 7 hidden layers
#define TILE_N 128
#define NTHR   512
#define WELTS  (NLAYER * HDIM * HDIM)   // 524288 fp16 weights in d_ws

typedef __attribute__((ext_vector_type(8))) _Float16 half8;
typedef __attribute__((ext_vector_type(4))) float float4v;

// tanh(x) = 1 - 2/(e^{2x}+1); saturation-safe (exp2->inf => 1, ->0 => -1).
__device__ __forceinline__ float fast_tanh(float x) {
    float z = __builtin_amdgcn_exp2f(x * 2.885390081777927f); // 2/ln2
    float r = __builtin_amdgcn_rcpf(z + 1.0f);
    return fmaf(-2.0f, r, 1.0f);
}

// swizzled LDS index for h[row][k] (fp16 elements)
__device__ __forceinline__ int swz(int row, int k) {
    return row * HDIM + ((((k >> 3) ^ (row & 7)) << 3) | (k & 7));
}

// ---- pre-pass: fp32 -> fp16 weight conversion into d_ws ----
// layout: dst[layer*65536 + o*256 + k]; layer 0 = W_in, layers 1..7 = W_h.
__global__ void convert_w_kernel(const float* __restrict__ W_in,
                                 const float* __restrict__ W_h,
                                 _Float16* __restrict__ dst)
{
    const int i = blockIdx.x * blockDim.x + threadIdx.x;  // 0 .. WELTS-1
    const float v = (i < HDIM * HDIM) ? W_in[i] : W_h[i - HDIM * HDIM];
    dst[i] = (_Float16)v;
}

__global__ __launch_bounds__(NTHR, 4)
void ffmlp_kernel(const float* __restrict__ tx,
                  const float* __restrict__ Bf,
                  const _Float16* __restrict__ Wall,   // d_ws, 8 layers fp16
                  const float* __restrict__ b_in,
                  const float* __restrict__ b_h,
                  const float* __restrict__ W_out,
                  const float* __restrict__ b_out,
                  float* __restrict__ out)
{
    __shared__ __align__(16) _Float16 hbuf[TILE_N * HDIM]; // 64 KB

    const int tid = threadIdx.x;
    const int row0 = blockIdx.x * TILE_N;

    // ---------------- stage 1: Fourier features -> hbuf ----------------
    {
        const float2* txv = (const float2*)tx;  // (N,2) fp32
        const float2* Bv  = (const float2*)Bf;  // (F,2) fp32
        const int f  = tid & (NFREQ - 1);
        const int rg = tid >> 7;                 // 0..3, each covers 32 rows
        const float2 bb = Bv[f];
        #pragma unroll 4
        for (int i = 0; i < 32; ++i) {
            const int row = rg * 32 + i;
            const float2 tt = txv[row0 + row];
            const float p = 6.283185307179586f * (tt.x * bb.x + tt.y * bb.y);
            float s, c;
            sincosf(p, &s, &c);
            hbuf[swz(row, f)]         = (_Float16)s;
            hbuf[swz(row, f + NFREQ)] = (_Float16)c;
        }
    }
    __syncthreads();

    // ---------------- stage 2: 8 dense layers, h stays in LDS ----------------
    // wave tile: 64 rows x 64 cols. 8 waves = 2 row-halves x 4 col-quarters.
    const int lane  = tid & 63;
    const int wave  = tid >> 6;
    const int rowH  = wave >> 2;       // 0..1
    const int colQ  = wave & 3;        // 0..3
    const int laneM = lane & 15;
    const int quad  = lane >> 4;

    for (int layer = 0; layer < NLAYER; ++layer) {
        const _Float16* Wl = Wall + layer * (HDIM * HDIM);
        const float*    bl = (layer == 0) ? b_in : b_h + (layer - 1) * HDIM;

        float4v acc[4][4];
        #pragma unroll
        for (int mt = 0; mt < 4; ++mt)
            #pragma unroll
            for (int nt = 0; nt < 4; ++nt)
                acc[mt][nt] = (float4v){0.f, 0.f, 0.f, 0.f};

        #pragma unroll 1
        for (int k0 = 0; k0 < HDIM; k0 += 32) {
            const int kk = k0 + quad * 8;
            half8 a[4], b[4];
            #pragma unroll
            for (int mt = 0; mt < 4; ++mt) {
                const int row = rowH * 64 + mt * 16 + laneM;
                a[mt] = *(const half8*)&hbuf[row * HDIM + (((kk >> 3) ^ (row & 7)) << 3)];
            }
            #pragma unroll
            for (int nt = 0; nt < 4; ++nt) {
                const int n = colQ * 64 + nt * 16 + laneM;
                b[nt] = *(const half8*)&Wl[n * HDIM + kk];
            }
            #pragma unroll
            for (int mt = 0; mt < 4; ++mt)
                #pragma unroll
                for (int nt = 0; nt < 4; ++nt)
                    acc[mt][nt] = __builtin_amdgcn_mfma_f32_16x16x32_f16(
                        a[mt], b[nt], acc[mt][nt], 0, 0, 0);
        }
        __syncthreads();   // all reads of hbuf complete before overwrite

        // epilogue: bias + tanh, write h_next back into hbuf (fp16)
        #pragma unroll
        for (int nt = 0; nt < 4; ++nt) {
            const int col = colQ * 64 + nt * 16 + laneM;
            const float bias = bl[col];
            #pragma unroll
            for (int mt = 0; mt < 4; ++mt) {
                const int rbase = rowH * 64 + mt * 16 + quad * 4;
                #pragma unroll
                for (int r = 0; r < 4; ++r) {
                    const float v = fast_tanh(acc[mt][nt][r] + bias);
                    hbuf[swz(rbase + r, col)] = (_Float16)v;
                }
            }
        }
        __syncthreads();   // hbuf fully rewritten before next layer reads
    }

    // ---------------- stage 3: output layer (matvec with W_out, fp32) ----------
    {
        const int row = tid >> 2;      // 0..127
        const int kq  = tid & 3;       // quarter of the k range
        float sum = 0.f;
        #pragma unroll 8
        for (int i = 0; i < 64; ++i) {
            const int k = kq * 64 + i;
            sum += (float)hbuf[swz(row, k)] * W_out[k];
        }
        sum += __shfl_xor(sum, 1);
        sum += __shfl_xor(sum, 2);
        if (kq == 0)
            out[row0 + row] = sum + b_out[0];
    }
}

extern "C" void kernel_launch(void* const* d_in, const int* in_sizes, int n_in,
                              void* d_out, int out_size, void* d_ws, size_t ws_size,
                              hipStream_t stream) {
    const float* tx    = (const float*)d_in[0];
    const float* Bf    = (const float*)d_in[1];
    const float* W_in  = (const float*)d_in[2];
    const float* b_in  = (const float*)d_in[3];
    const float* W_h   = (const float*)d_in[4];
    const float* b_h   = (const float*)d_in[5];
    const float* W_out = (const float*)d_in[6];
    const float* b_out = (const float*)d_in[7];
    float* out = (float*)d_out;

    _Float16* Wall = (_Float16*)d_ws;   // needs WELTS*2 = 1 MiB of scratch

    const int npts   = in_sizes[0] / 2;        // 131072
    const int blocks = npts / TILE_N;          // 1024

    // pre-pass: convert W_in + W_h to fp16 (WELTS = 524288 elements)
    convert_w_kernel<<<WELTS / NTHR, NTHR, 0, stream>>>(W_in, W_h, Wall);

    ffmlp_kernel<<<blocks, NTHR, 0, stream>>>(tx, Bf, Wall, b_in, b_h,
                                              W_out, b_out, out);
}

// Round 4
// 324.741 us; speedup vs baseline: 1.2035x; 1.2035x over previous
//
#include <hip/hip_runtime.h>

// FourierFeatureMLP fused kernel for MI355X (gfx950). Round 4 (r3 + compile fix).
//
// vs round 2 (363 us, MfmaUtil 16%, VALUBusy 33%):
//  - HW trig: sin(2*pi*r) = v_sin_f32(fract(r)) (revolutions!). Replaces
//    ~100-instr libm sincosf with ~4 instr. Biggest VALU cut.
//  - Swapped MFMA operands: A = W, B = h. D layout then gives each lane
//    4 CONSECUTIVE hidden units for one point -> epilogue writes
//    ds_write_b64 (half4) instead of 4x ds_write_b16, with packed
//    v_cvt_pkrtz f32->f16x2 converts (bit_cast from __fp16v2 to _Float16v2).
//  - Stage 1: each thread owns a freq PAIR -> half2 LDS writes, float4 B
//    loads, wave-uniform (broadcast) tx loads.
//
// Layouts (MFMA 16x16x32, learn_hip-verified):
//   A: lane holds A[m=lane&15][k=quad*8+j]  -> W[o][k] row o = base+laneM
//   B: lane holds B[k=quad*8+j][n=lane&15]  -> h[pt_row=base+laneM][k..k+7]
//   D: n(point)=lane&15, m(hidden unit)=quad*4+reg -> 4 consecutive units.
//
// hbuf swizzle: chunk' = chunk ^ (row&7) (16B chunks) breaks the 512-B
// row-stride bank pattern for the 16-lane row-parallel b128 reads.

#define HDIM   256
#define NFREQ  128
#define NLAYER 8
#define TILE_N 128
#define NTHR   512
#define WELTS  (NLAYER * HDIM * HDIM)

typedef __attribute__((ext_vector_type(8))) _Float16 half8;
typedef __attribute__((ext_vector_type(4))) _Float16 half4;
typedef __attribute__((ext_vector_type(2))) _Float16 half2;
typedef __attribute__((ext_vector_type(2))) __fp16   fp16v2;  // pkrtz return type
typedef __attribute__((ext_vector_type(4))) float float4v;

__device__ __forceinline__ half2 pk2(float a, float b) {
    return __builtin_bit_cast(half2, __builtin_amdgcn_cvt_pkrtz(a, b));
}

// tanh(x) = 1 - 2/(e^{2x}+1); saturation-safe.
__device__ __forceinline__ float fast_tanh(float x) {
    float z = __builtin_amdgcn_exp2f(x * 2.885390081777927f); // 2/ln2
    float r = __builtin_amdgcn_rcpf(z + 1.0f);
    return fmaf(-2.0f, r, 1.0f);
}

// swizzled LDS element index for h[row][k]
__device__ __forceinline__ int swz(int row, int k) {
    return row * HDIM + ((((k >> 3) ^ (row & 7)) << 3) | (k & 7));
}

// ---- pre-pass: fp32 -> fp16 weights into d_ws (layer 0 = W_in, 1..7 = W_h)
__global__ void convert_w_kernel(const float* __restrict__ W_in,
                                 const float* __restrict__ W_h,
                                 _Float16* __restrict__ dst)
{
    const int i = blockIdx.x * blockDim.x + threadIdx.x;
    const float v = (i < HDIM * HDIM) ? W_in[i] : W_h[i - HDIM * HDIM];
    dst[i] = (_Float16)v;
}

__global__ __launch_bounds__(NTHR, 4)
void ffmlp_kernel(const float* __restrict__ tx,
                  const float* __restrict__ Bf,
                  const _Float16* __restrict__ Wall,
                  const float* __restrict__ b_in,
                  const float* __restrict__ b_h,
                  const float* __restrict__ W_out,
                  const float* __restrict__ b_out,
                  float* __restrict__ out)
{
    __shared__ __align__(16) _Float16 hbuf[TILE_N * HDIM]; // 64 KB

    const int tid  = threadIdx.x;
    const int row0 = blockIdx.x * TILE_N;

    // ---------------- stage 1: Fourier features -> hbuf ----------------
    // sin(2*pi*r) = v_sin(fract(r)) : argument stays in revolutions.
    {
        const float2* txv  = (const float2*)tx;
        const int pair = tid & 63;          // freq pair id (lane = pair)
        const int rg   = tid >> 6;          // wave id = row group (16 rows)
        const float4 Bp = *(const float4*)&Bf[4 * pair]; // B[2p], B[2p+1]
        const int f0 = 2 * pair;
        #pragma unroll 4
        for (int i = 0; i < 16; ++i) {
            const int row = rg * 16 + i;
            const float2 t = txv[row0 + row];          // wave-uniform load
            float r0 = t.x * Bp.x + t.y * Bp.y;        // revolutions
            float r1 = t.x * Bp.z + t.y * Bp.w;
            r0 = __builtin_amdgcn_fractf(r0);
            r1 = __builtin_amdgcn_fractf(r1);
            half2 sp = pk2(__builtin_amdgcn_sinf(r0), __builtin_amdgcn_sinf(r1));
            half2 cp = pk2(__builtin_amdgcn_cosf(r0), __builtin_amdgcn_cosf(r1));
            *(half2*)&hbuf[swz(row, f0)]         = sp;
            *(half2*)&hbuf[swz(row, f0 + NFREQ)] = cp;
        }
    }
    __syncthreads();

    // ---------------- stage 2: 8 dense layers, h stays in LDS ----------------
    // waves: 4 hidden-unit quarters (nQ) x 2 point halves (pH).
    // wave tile: 64 hidden units x 64 points = acc[4][4] frags.
    const int lane  = tid & 63;
    const int wave  = tid >> 6;
    const int nQ    = wave & 3;
    const int pH    = wave >> 2;
    const int laneM = lane & 15;
    const int quad  = lane >> 4;

    for (int layer = 0; layer < NLAYER; ++layer) {
        const _Float16* Wl = Wall + layer * (HDIM * HDIM);
        const float*    bl = (layer == 0) ? b_in : b_h + (layer - 1) * HDIM;

        float4v acc[4][4];
        #pragma unroll
        for (int at = 0; at < 4; ++at)
            #pragma unroll
            for (int pt = 0; pt < 4; ++pt)
                acc[at][pt] = (float4v){0.f, 0.f, 0.f, 0.f};

        #pragma unroll 1
        for (int k0 = 0; k0 < HDIM; k0 += 32) {
            const int kk = k0 + quad * 8;
            half8 a[4], b[4];
            #pragma unroll
            for (int at = 0; at < 4; ++at) {
                const int o = nQ * 64 + at * 16 + laneM;      // W row
                a[at] = *(const half8*)&Wl[o * HDIM + kk];
            }
            #pragma unroll
            for (int pt = 0; pt < 4; ++pt) {
                const int m = pH * 64 + pt * 16 + laneM;      // point row
                b[pt] = *(const half8*)&hbuf[m * HDIM + (((kk >> 3) ^ (m & 7)) << 3)];
            }
            #pragma unroll
            for (int at = 0; at < 4; ++at)
                #pragma unroll
                for (int pt = 0; pt < 4; ++pt)
                    acc[at][pt] = __builtin_amdgcn_mfma_f32_16x16x32_f16(
                        a[at], b[pt], acc[at][pt], 0, 0, 0);
        }
        __syncthreads();   // all reads of hbuf done before overwrite

        // epilogue: bias + tanh, packed half4 writes (4 consecutive units)
        #pragma unroll
        for (int at = 0; at < 4; ++at) {
            const int u0 = nQ * 64 + at * 16 + quad * 4;      // unit base
            const float4 b4 = *(const float4*)&bl[u0];
            #pragma unroll
            for (int pt = 0; pt < 4; ++pt) {
                const int m = pH * 64 + pt * 16 + laneM;      // point
                const float v0 = fast_tanh(acc[at][pt].x + b4.x);
                const float v1 = fast_tanh(acc[at][pt].y + b4.y);
                const float v2 = fast_tanh(acc[at][pt].z + b4.z);
                const float v3 = fast_tanh(acc[at][pt].w + b4.w);
                const half2 lo = pk2(v0, v1);
                const half2 hi = pk2(v2, v3);
                half4 pkv;
                pkv.x = lo.x; pkv.y = lo.y; pkv.z = hi.x; pkv.w = hi.y;
                *(half4*)&hbuf[swz(m, u0)] = pkv;             // ds_write_b64
            }
        }
        __syncthreads();
    }

    // ---------------- stage 3: output matvec ----------------
    {
        const int row = tid >> 2;       // 0..127
        const int kq  = tid & 3;
        float sum = 0.f;
        #pragma unroll 8
        for (int i = 0; i < 64; ++i) {
            const int k = kq * 64 + i;
            sum += (float)hbuf[swz(row, k)] * W_out[k];
        }
        sum += __shfl_xor(sum, 1);
        sum += __shfl_xor(sum, 2);
        if (kq == 0)
            out[row0 + row] = sum + b_out[0];
    }
}

extern "C" void kernel_launch(void* const* d_in, const int* in_sizes, int n_in,
                              void* d_out, int out_size, void* d_ws, size_t ws_size,
                              hipStream_t stream) {
    const float* tx    = (const float*)d_in[0];
    const float* Bf    = (const float*)d_in[1];
    const float* W_in  = (const float*)d_in[2];
    const float* b_in  = (const float*)d_in[3];
    const float* W_h   = (const float*)d_in[4];
    const float* b_h   = (const float*)d_in[5];
    const float* W_out = (const float*)d_in[6];
    const float* b_out = (const float*)d_in[7];
    float* out = (float*)d_out;

    _Float16* Wall = (_Float16*)d_ws;   // 1 MiB scratch

    const int npts   = in_sizes[0] / 2;
    const int blocks = npts / TILE_N;

    convert_w_kernel<<<WELTS / NTHR, NTHR, 0, stream>>>(W_in, W_h, Wall);
    ffmlp_kernel<<<blocks, NTHR, 0, stream>>>(tx, Bf, Wall, b_in, b_h,
                                              W_out, b_out, out);
}

// Round 5
// 320.240 us; speedup vs baseline: 1.2204x; 1.0141x over previous
//
#include <hip/hip_runtime.h>

// FourierFeatureMLP fused kernel for MI355X (gfx950). Round 5.
//
// vs round 4 (290 us kernel; MfmaUtil 20.5%, VALUBusy 34.8%, ~40% stall):
// root cause of stall = only 2 blocks/CU (64 KB LDS each) in barrier
// lockstep: K-loop (matrix pipe) and tanh epilogue (VALU+trans pipe)
// alternate instead of overlapping across blocks (m114 overlap needs
// independent co-resident waves). Fix: TILE_N=64, 256 thr/block, 32 KB
// LDS -> 4 blocks/CU. Per-wave work unchanged.
// Also: bias folded into exp2 arg (fma), stage-3 matvec uses b128 reads.
//
// Layouts (MFMA 16x16x32, learn_hip-verified):
//   A: lane holds A[m=lane&15][k=quad*8+j]  -> W[o][k] row o = base+laneM
//   B: lane holds B[k=quad*8+j][n=lane&15]  -> h[pt=base+laneM][k..k+7]
//   D: n(point)=lane&15, m(hidden unit)=quad*4+reg -> 4 consecutive units.
//
// hbuf swizzle: 16B chunk' = chunk ^ (row&7) breaks the 512-B row-stride
// bank pattern for row-parallel b128 accesses.

#define HDIM   256
#define NFREQ  128
#define NLAYER 8
#define TILE_N 64
#define NTHR   256
#define WELTS  (NLAYER * HDIM * HDIM)

typedef __attribute__((ext_vector_type(8))) _Float16 half8;
typedef __attribute__((ext_vector_type(4))) _Float16 half4;
typedef __attribute__((ext_vector_type(2))) _Float16 half2;
typedef __attribute__((ext_vector_type(4))) float float4v;

__device__ __forceinline__ half2 pk2(float a, float b) {
    return __builtin_bit_cast(half2, __builtin_amdgcn_cvt_pkrtz(a, b));
}

// tanh(acc + b) with pre-scaled bias bK = b * 2/ln2:
// t = acc*K + bK; z = 2^t; r = 1/(1+z); tanh = 1 - 2r. Saturation-safe.
#define TANH_K 2.885390081777927f
__device__ __forceinline__ float fast_tanh_fused(float acc, float bK) {
    float z = __builtin_amdgcn_exp2f(fmaf(acc, TANH_K, bK));
    float r = __builtin_amdgcn_rcpf(z + 1.0f);
    return fmaf(-2.0f, r, 1.0f);
}

// swizzled LDS element index for h[row][k]
__device__ __forceinline__ int swz(int row, int k) {
    return row * HDIM + ((((k >> 3) ^ (row & 7)) << 3) | (k & 7));
}

// ---- pre-pass: fp32 -> fp16 weights into d_ws (layer 0 = W_in, 1..7 = W_h)
__global__ void convert_w_kernel(const float* __restrict__ W_in,
                                 const float* __restrict__ W_h,
                                 _Float16* __restrict__ dst)
{
    const int i = blockIdx.x * blockDim.x + threadIdx.x;
    const float v = (i < HDIM * HDIM) ? W_in[i] : W_h[i - HDIM * HDIM];
    dst[i] = (_Float16)v;
}

__global__ __launch_bounds__(NTHR, 4)
void ffmlp_kernel(const float* __restrict__ tx,
                  const float* __restrict__ Bf,
                  const _Float16* __restrict__ Wall,
                  const float* __restrict__ b_in,
                  const float* __restrict__ b_h,
                  const float* __restrict__ W_out,
                  const float* __restrict__ b_out,
                  float* __restrict__ out)
{
    __shared__ __align__(16) _Float16 hbuf[TILE_N * HDIM]; // 32 KB

    const int tid  = threadIdx.x;
    const int row0 = blockIdx.x * TILE_N;
    const int lane = tid & 63;
    const int wave = tid >> 6;           // 0..3

    // ---------------- stage 1: Fourier features -> hbuf ----------------
    // sin(2*pi*r) = v_sin(fract(r)) : argument in revolutions.
    {
        const float2* txv = (const float2*)tx;
        const int pair = lane;               // freq pair 0..63 (f0 = 2*pair)
        const float4 Bp = *(const float4*)&Bf[4 * pair];
        const int f0 = 2 * pair;
        #pragma unroll 4
        for (int i = 0; i < 16; ++i) {
            const int row = wave * 16 + i;
            const float2 t = txv[row0 + row];          // wave-uniform load
            float r0 = t.x * Bp.x + t.y * Bp.y;        // revolutions
            float r1 = t.x * Bp.z + t.y * Bp.w;
            r0 = __builtin_amdgcn_fractf(r0);
            r1 = __builtin_amdgcn_fractf(r1);
            half2 sp = pk2(__builtin_amdgcn_sinf(r0), __builtin_amdgcn_sinf(r1));
            half2 cp = pk2(__builtin_amdgcn_cosf(r0), __builtin_amdgcn_cosf(r1));
            *(half2*)&hbuf[swz(row, f0)]         = sp;
            *(half2*)&hbuf[swz(row, f0 + NFREQ)] = cp;
        }
    }
    __syncthreads();

    // ---------------- stage 2: 8 dense layers, h stays in LDS ----------------
    // 4 waves = 4 hidden-unit quarters (nQ). Wave tile: 64 units x 64 points.
    const int nQ    = wave;
    const int laneM = lane & 15;
    const int quad  = lane >> 4;

    for (int layer = 0; layer < NLAYER; ++layer) {
        const _Float16* Wl = Wall + layer * (HDIM * HDIM);
        const float*    bl = (layer == 0) ? b_in : b_h + (layer - 1) * HDIM;

        float4v acc[4][4];
        #pragma unroll
        for (int at = 0; at < 4; ++at)
            #pragma unroll
            for (int pt = 0; pt < 4; ++pt)
                acc[at][pt] = (float4v){0.f, 0.f, 0.f, 0.f};

        #pragma unroll 1
        for (int k0 = 0; k0 < HDIM; k0 += 32) {
            const int kk = k0 + quad * 8;
            half8 a[4], b[4];
            #pragma unroll
            for (int at = 0; at < 4; ++at) {
                const int o = nQ * 64 + at * 16 + laneM;      // W row
                a[at] = *(const half8*)&Wl[o * HDIM + kk];
            }
            #pragma unroll
            for (int pt = 0; pt < 4; ++pt) {
                const int m = pt * 16 + laneM;                // point row
                b[pt] = *(const half8*)&hbuf[m * HDIM + (((kk >> 3) ^ (m & 7)) << 3)];
            }
            #pragma unroll
            for (int at = 0; at < 4; ++at)
                #pragma unroll
                for (int pt = 0; pt < 4; ++pt)
                    acc[at][pt] = __builtin_amdgcn_mfma_f32_16x16x32_f16(
                        a[at], b[pt], acc[at][pt], 0, 0, 0);
        }
        __syncthreads();   // all reads of hbuf done before overwrite

        // epilogue: fused bias+tanh, packed half4 writes (4 consecutive units)
        #pragma unroll
        for (int at = 0; at < 4; ++at) {
            const int u0 = nQ * 64 + at * 16 + quad * 4;      // unit base
            float4 b4 = *(const float4*)&bl[u0];
            b4.x *= TANH_K; b4.y *= TANH_K; b4.z *= TANH_K; b4.w *= TANH_K;
            #pragma unroll
            for (int pt = 0; pt < 4; ++pt) {
                const int m = pt * 16 + laneM;                // point
                const float v0 = fast_tanh_fused(acc[at][pt].x, b4.x);
                const float v1 = fast_tanh_fused(acc[at][pt].y, b4.y);
                const float v2 = fast_tanh_fused(acc[at][pt].z, b4.z);
                const float v3 = fast_tanh_fused(acc[at][pt].w, b4.w);
                const half2 lo = pk2(v0, v1);
                const half2 hi = pk2(v2, v3);
                half4 pkv;
                pkv.x = lo.x; pkv.y = lo.y; pkv.z = hi.x; pkv.w = hi.y;
                *(half4*)&hbuf[swz(m, u0)] = pkv;             // ds_write_b64
            }
        }
        __syncthreads();
    }

    // ---------------- stage 3: output matvec (b128 reads) ----------------
    {
        const int row = tid >> 2;       // 0..63
        const int cq  = tid & 3;        // chunk quarter (8 chunks each)
        float sum = 0.f;
        #pragma unroll
        for (int j = 0; j < 8; ++j) {
            const int c = cq * 8 + j;   // logical 8-elem chunk
            const half8 hv = *(const half8*)&hbuf[row * HDIM + ((c ^ (row & 7)) << 3)];
            const float4 w0 = *(const float4*)&W_out[c * 8];
            const float4 w1 = *(const float4*)&W_out[c * 8 + 4];
            sum += (float)hv[0] * w0.x + (float)hv[1] * w0.y +
                   (float)hv[2] * w0.z + (float)hv[3] * w0.w +
                   (float)hv[4] * w1.x + (float)hv[5] * w1.y +
                   (float)hv[6] * w1.z + (float)hv[7] * w1.w;
        }
        sum += __shfl_xor(sum, 1);
        sum += __shfl_xor(sum, 2);
        if (cq == 0)
            out[row0 + row] = sum + b_out[0];
    }
}

extern "C" void kernel_launch(void* const* d_in, const int* in_sizes, int n_in,
                              void* d_out, int out_size, void* d_ws, size_t ws_size,
                              hipStream_t stream) {
    const float* tx    = (const float*)d_in[0];
    const float* Bf    = (const float*)d_in[1];
    const float* W_in  = (const float*)d_in[2];
    const float* b_in  = (const float*)d_in[3];
    const float* W_h   = (const float*)d_in[4];
    const float* b_h   = (const float*)d_in[5];
    const float* W_out = (const float*)d_in[6];
    const float* b_out = (const float*)d_in[7];
    float* out = (float*)d_out;

    _Float16* Wall = (_Float16*)d_ws;   // 1 MiB scratch

    const int npts   = in_sizes[0] / 2;
    const int blocks = npts / TILE_N;   // 2048

    convert_w_kernel<<<WELTS / NTHR, NTHR, 0, stream>>>(W_in, W_h, Wall);
    ffmlp_kernel<<<blocks, NTHR, 0, stream>>>(tx, Bf, Wall, b_in, b_h,
                                              W_out, b_out, out);
}